// Round 3
// baseline (478.469 us; speedup 1.0000x reference)
//
#include <hip/hip_runtime.h>
#include <cstdint>
#include <math.h>

#define N_FRAMES 16777216          // 2^24
#define MAX_BEATS (N_FRAMES / 8)   // 2097152
#define CHUNK 4096
#define NTHREADS 256
#define NBLOCKS (N_FRAMES / CHUNK) // 4096

typedef unsigned long long u64;
typedef unsigned int u32;

// Lookback status: bits 63..62 = state (0 invalid, 1 aggregate, 2 prefix), low 32 = value
#define ST_AGG (1ull << 62)
#define ST_PRE (2ull << 62)

// peak test straight from the reference: x[j]>0 and x[j]==max(window +-3, -inf pad)
__device__ __forceinline__ bool peak_at_global(const float* __restrict__ x, int j) {
  if (j < 0 || j >= N_FRAMES) return false;
  const float c = x[j];
  if (!(c > 0.0f)) return false;
  float m = -INFINITY;
#pragma unroll
  for (int d = -3; d <= 3; ++d) {
    if (d == 0) continue;
    const int k = j + d;
    if (k >= 0 && k < N_FRAMES) m = fmaxf(m, x[k]);
  }
  return c >= m;
}

__global__ __launch_bounds__(NTHREADS) void k_fused(const float* __restrict__ x,
                                                    u64* __restrict__ status,
                                                    u32* __restrict__ ticket,
                                                    float* __restrict__ out) {
  __shared__ u32 m16[NTHREADS];   // 16-bit peak mask per thread (16 consecutive elems)
  __shared__ u64 lm[64];          // 64-bit masks per 64-element row
  __shared__ int s_bid;
  __shared__ u32 s_pm1;           // peak at g0-1

  if (threadIdx.x == 0) s_bid = (int)atomicAdd(ticket, 1u);
  __syncthreads();
  const int b = s_bid;
  const int g0 = b * CHUNK;
  const int t = threadIdx.x;
  const int gbase = g0 + t * 16;

  // register window: v[k] = x[gbase - 4 + k], k in [0,24)
  float v[24];
  if (gbase - 4 >= 0 && gbase + 20 <= N_FRAMES) {
    const float4* p = reinterpret_cast<const float4*>(x + gbase - 4);
#pragma unroll
    for (int k = 0; k < 6; ++k) {
      const float4 f = p[k];
      v[4 * k + 0] = f.x; v[4 * k + 1] = f.y; v[4 * k + 2] = f.z; v[4 * k + 3] = f.w;
    }
  } else {
#pragma unroll
    for (int k = 0; k < 24; ++k) {
      const int gi = gbase - 4 + k;
      v[k] = (gi >= 0 && gi < N_FRAMES) ? x[gi] : -INFINITY;
    }
  }

  u32 pm = 0;
#pragma unroll
  for (int e = 0; e < 16; ++e) {
    const float c = v[e + 4];
    float m = fmaxf(fmaxf(v[e + 1], v[e + 2]), fmaxf(v[e + 3], v[e + 5]));
    m = fmaxf(m, fmaxf(v[e + 6], v[e + 7]));
    pm |= (c > 0.0f && c >= m) ? (1u << e) : 0u;
  }
  m16[t] = pm;
  if (t == 0) {   // peak at element gbase-1 (window v[0..6], center v[3])
    const float c = v[3];
    float m = fmaxf(fmaxf(v[0], v[1]), fmaxf(v[2], v[4]));
    m = fmaxf(m, fmaxf(v[5], v[6]));
    s_pm1 = (c > 0.0f && c >= m) ? 1u : 0u;
  }
  __syncthreads();

  if (t < 64) {
    const u64 m = (u64)m16[4 * t] | ((u64)m16[4 * t + 1] << 16) |
                  ((u64)m16[4 * t + 2] << 32) | ((u64)m16[4 * t + 3] << 48);
    lm[t] = m;
  }
  __syncthreads();

  if (t < 64) {
    const u64 m = lm[t];
    const u64 carry = (t == 0) ? (u64)s_pm1 : (u64)((m16[4 * t - 1] >> 15) & 1u);
    u64 sm = m & ~((m << 1) | carry);   // run-start mask
    const int cnt = __popcll(sm);

    // intra-block exclusive scan over the 64 rows
    int incl = cnt;
#pragma unroll
    for (int off = 1; off < 64; off <<= 1) {
      const int vv = __shfl_up(incl, off, 64);
      if (t >= off) incl += vv;
    }
    const int agg = __shfl(incl, 63, 64);

    // publish aggregate early
    if (t == 0 && b > 0)
      __hip_atomic_store(&status[b], ST_AGG | (u64)(u32)agg,
                         __ATOMIC_RELEASE, __HIP_MEMORY_SCOPE_AGENT);

    // wave-parallel decoupled lookback
    int exclv = 0;
    if (b > 0) {
      int j = b - 1;
      for (;;) {
        const int myj = j - t;
        u64 stv = 0;
        if (myj >= 0) {
          do {
            stv = __hip_atomic_load(&status[myj], __ATOMIC_ACQUIRE, __HIP_MEMORY_SCOPE_AGENT);
          } while ((stv >> 62) == 0ull);
        }
        const u64 pref_ballot = __ballot(myj >= 0 && (stv >> 62) == 2ull);
        const int firstPref = pref_ballot ? __builtin_ctzll(pref_ballot) : 64;
        int contrib = (myj >= 0 && t <= firstPref) ? (int)(stv & 0xFFFFFFFFull) : 0;
#pragma unroll
        for (int off = 32; off; off >>= 1) contrib += __shfl_down(contrib, off, 64);
        contrib = __shfl(contrib, 0, 64);
        exclv += contrib;
        if (firstPref < 64) break;
        j -= 64;
        if (j < 0) break;  // unreachable: block 0 publishes PREFIX
      }
    }
    if (t == 0)
      __hip_atomic_store(&status[b], ST_PRE | (u64)(u32)(exclv + agg),
                         __ATOMIC_RELEASE, __HIP_MEMORY_SCOPE_AGENT);

    // emit
    int sid = exclv + incl - cnt;
    const int gb2 = g0 + t * 64;
    while (sm) {
      const int s = __builtin_ctzll(sm);
      sm &= sm - 1;
      const int i0 = gb2 + s;
      const u64 above = m >> s;          // bit 0 = this peak
      const int len = (~above == 0ull) ? (64 - s) : __builtin_ctzll(~above);
      int end = i0 + len - 1;
      if (s + len == 64) {               // run continues into next row (ties; rare)
        bool crossed_chunk = true;
        for (int idx = t + 1; idx < 64; ++idx) {
          const u64 mm = lm[idx];
          if (~mm == 0ull) { end += 64; }
          else { end += __builtin_ctzll(~mm); crossed_chunk = false; break; }
        }
        if (crossed_chunk) {             // into next chunk: walk global (rare)
          int j = g0 + CHUNK;
          while (peak_at_global(x, j)) { ++end; ++j; }
        }
      }
      if (sid < MAX_BEATS)
        out[sid] = (float)(((double)i0 + (double)end) * 0.5);
      ++sid;
    }

    // last chunk fills the unused tail with -1 (empty for dense-peak inputs)
    if (b == NBLOCKS - 1) {
      const int total = exclv + agg;
      for (int i = total + t; i < MAX_BEATS; i += 64) out[i] = -1.0f;
    }
  }
}

extern "C" void kernel_launch(void* const* d_in, const int* in_sizes, int n_in,
                              void* d_out, int out_size, void* d_ws, size_t ws_size,
                              hipStream_t stream) {
  const float* x = (const float*)d_in[0];
  float* out = (float*)d_out;

  u64* status = (u64*)d_ws;                 // NBLOCKS u64
  u32* ticket = (u32*)(status + NBLOCKS);   // 1 u32

  hipMemsetAsync(d_ws, 0, NBLOCKS * sizeof(u64) + sizeof(u32), stream);
  k_fused<<<NBLOCKS, NTHREADS, 0, stream>>>(x, status, ticket, out);
}

// Round 4
// 30.411 us; speedup vs baseline: 15.7336x; 15.7336x over previous
//
#include <hip/hip_runtime.h>
#include <cstdint>
#include <math.h>

#define N_FRAMES 16777216          // 2^24
#define MAX_BEATS (N_FRAMES / 8)   // 2097152
#define CHUNK 4096
#define NTHREADS 256
#define NBLOCKS (N_FRAMES / CHUNK) // 4096
#define TOTAL_MASKS ((size_t)NBLOCKS * 64)

typedef unsigned long long u64;
typedef unsigned int u32;

// peak test straight from the reference: x[j]>0 and x[j]==max(window +-3, -inf pad)
__device__ __forceinline__ bool peak_at_global(const float* __restrict__ x, int j) {
  if (j < 0 || j >= N_FRAMES) return false;
  const float c = x[j];
  if (!(c > 0.0f)) return false;
  float m = -INFINITY;
#pragma unroll
  for (int d = -3; d <= 3; ++d) {
    if (d == 0) continue;
    const int k = j + d;
    if (k >= 0 && k < N_FRAMES) m = fmaxf(m, x[k]);
  }
  return c >= m;
}

// k_count: register-window stencil -> 16-bit masks -> pack to u64 rows -> counts
__global__ __launch_bounds__(NTHREADS) void k_count(const float* __restrict__ x,
                                                    int* __restrict__ blockCounts,
                                                    u64* __restrict__ masks) {
  __shared__ u32 m16[NTHREADS];
  __shared__ u32 s_pm1;           // peak at g0-1
  const int b = blockIdx.x;
  const int g0 = b * CHUNK;
  const int t = threadIdx.x;
  const int gbase = g0 + t * 16;

  // v[k] = x[gbase - 4 + k], k in [0,24)
  float v[24];
  if (gbase - 4 >= 0 && gbase + 20 <= N_FRAMES) {
    const float4* p = reinterpret_cast<const float4*>(x + gbase - 4);
#pragma unroll
    for (int k = 0; k < 6; ++k) {
      const float4 f = p[k];
      v[4 * k + 0] = f.x; v[4 * k + 1] = f.y; v[4 * k + 2] = f.z; v[4 * k + 3] = f.w;
    }
  } else {
#pragma unroll
    for (int k = 0; k < 24; ++k) {
      const int gi = gbase - 4 + k;
      v[k] = (gi >= 0 && gi < N_FRAMES) ? x[gi] : -INFINITY;
    }
  }

  u32 pm = 0;
#pragma unroll
  for (int e = 0; e < 16; ++e) {
    const float c = v[e + 4];
    float m = fmaxf(fmaxf(v[e + 1], v[e + 2]), fmaxf(v[e + 3], v[e + 5]));
    m = fmaxf(m, fmaxf(v[e + 6], v[e + 7]));
    pm |= (c > 0.0f && c >= m) ? (1u << e) : 0u;
  }
  m16[t] = pm;
  if (t == 0) {  // peak at g0-1: center v[3], window v[0..6]
    const float c = v[3];
    float m = fmaxf(fmaxf(v[0], v[1]), fmaxf(v[2], v[4]));
    m = fmaxf(m, fmaxf(v[5], v[6]));
    s_pm1 = (c > 0.0f && c >= m) ? 1u : 0u;
  }
  __syncthreads();

  if (t < 64) {
    const u64 m = (u64)m16[4 * t] | ((u64)m16[4 * t + 1] << 16) |
                  ((u64)m16[4 * t + 2] << 32) | ((u64)m16[4 * t + 3] << 48);
    masks[((size_t)b << 6) + t] = m;
    const u64 carry = (t == 0) ? (u64)s_pm1 : (u64)((m16[4 * t - 1] >> 15) & 1u);
    int cnt = __popcll(m & ~((m << 1) | carry));
#pragma unroll
    for (int off = 32; off; off >>= 1) cnt += __shfl_down(cnt, off, 64);
    if (t == 0) blockCounts[b] = cnt;
  }
}

// single-block exclusive scan over NBLOCKS counts; offsets[NBLOCKS] = total
__global__ __launch_bounds__(NTHREADS) void k_scan(const int* __restrict__ counts,
                                                   int* __restrict__ offsets) {
  __shared__ int wtot[4];
  const int t = threadIdx.x;
  const int w = t >> 6, lane = t & 63;
  int local[16];
  int s = 0;
#pragma unroll
  for (int e = 0; e < 16; ++e) { local[e] = counts[t * 16 + e]; s += local[e]; }
  int incl = s;
#pragma unroll
  for (int off = 1; off < 64; off <<= 1) {
    const int vv = __shfl_up(incl, off, 64);
    if (lane >= off) incl += vv;
  }
  if (lane == 63) wtot[w] = incl;
  __syncthreads();
  int wadd = 0;
  for (int ww = 0; ww < w; ++ww) wadd += wtot[ww];
  int excl = wadd + incl - s;
#pragma unroll
  for (int e = 0; e < 16; ++e) { offsets[t * 16 + e] = excl; excl += local[e]; }
  if (t == NTHREADS - 1) offsets[NBLOCKS] = excl;  // grand total
}

// k_emit: 4 waves/block, wave w owns chunk blockIdx.x*4+w; lane owns one u64 row.
// Also fills the -1 tail (indices >= total), disjoint from section writes.
__global__ __launch_bounds__(NTHREADS) void k_emit(const u64* __restrict__ masks,
                                                   const int* __restrict__ offsets,
                                                   float* __restrict__ out) {
  const int w = threadIdx.x >> 6, lane = threadIdx.x & 63;
  const int b = blockIdx.x * 4 + w;
  const size_t mi = ((size_t)b << 6) + lane;
  const u64 m = masks[mi];
  const u32 myb63 = (u32)(m >> 63);
  u32 prevb = __shfl_up(myb63, 1, 64);
  if (lane == 0) prevb = (b == 0) ? 0u : (u32)(masks[mi - 1] >> 63);
  u64 sm = m & ~((m << 1) | (u64)prevb);
  const int cnt = __popcll(sm);

  int incl = cnt;
#pragma unroll
  for (int off = 1; off < 64; off <<= 1) {
    const int vv = __shfl_up(incl, off, 64);
    if (lane >= off) incl += vv;
  }
  int sid = offsets[b] + incl - cnt;

  const int gbase = b * CHUNK + lane * 64;
  while (sm) {
    const int s = __builtin_ctzll(sm);
    sm &= sm - 1;
    const int i0 = gbase + s;
    const u64 above = m >> s;            // bit 0 = this peak
    const int len = (~above == 0ull) ? (64 - s) : __builtin_ctzll(~above);
    int end = i0 + len - 1;
    if (s + len == 64) {                 // run continues into next row (ties; rare)
      size_t idx = mi + 1;
      while (idx < TOTAL_MASKS) {
        const u64 mm = masks[idx];
        if (~mm == 0ull) { end += 64; ++idx; }
        else { end += __builtin_ctzll(~mm); break; }
      }
    }
    if (sid < MAX_BEATS)
      out[sid] = (float)(((double)i0 + (double)end) * 0.5);
    ++sid;
  }

  // -1 tail fill: block covers out[blockIdx.x*2048 .. +2048)
  const int total = offsets[NBLOCKS];
  const int lo = blockIdx.x * (MAX_BEATS / (NBLOCKS / 4));
  const int hi = lo + (MAX_BEATS / (NBLOCKS / 4));
  for (int i = max(lo, total) + (int)threadIdx.x; i < hi; i += NTHREADS)
    out[i] = -1.0f;
}

extern "C" void kernel_launch(void* const* d_in, const int* in_sizes, int n_in,
                              void* d_out, int out_size, void* d_ws, size_t ws_size,
                              hipStream_t stream) {
  const float* x = (const float*)d_in[0];
  float* out = (float*)d_out;

  u64* masks = (u64*)d_ws;                         // 2 MiB
  int* counts = (int*)(masks + TOTAL_MASKS);       // NBLOCKS ints
  int* offsets = counts + NBLOCKS;                 // NBLOCKS+1 ints

  k_count<<<NBLOCKS, NTHREADS, 0, stream>>>(x, counts, masks);
  k_scan<<<1, NTHREADS, 0, stream>>>(counts, offsets);
  k_emit<<<NBLOCKS / 4, NTHREADS, 0, stream>>>(masks, offsets, out);
}